// Round 12
// baseline (355.680 us; speedup 1.0000x reference)
//
#include <hip/hip_runtime.h>
#include <hip/hip_bf16.h>
#include <cstddef>

#define NG   50000
#define ND   20000
#define DH   128
#define EGG  800000
#define EGDA 400000
#define ELAB 200000

#define B1G 391
#define B1D 157
#define TB  939
#define TBP 940
#define PB0 0
#define PB1 (NG+1)
#define PB2 (NG+1+ND+1)

typedef __hip_bfloat16  bf16;
typedef __attribute__((ext_vector_type(8))) short bf16x8;
typedef __attribute__((ext_vector_type(4))) float f32x4;
typedef __attribute__((ext_vector_type(2))) float f32x2;

__device__ __forceinline__ float bf2f(short s){
  return __uint_as_float(((unsigned)(unsigned short)s) << 16);
}
__device__ __forceinline__ unsigned short f2b(float x){
  unsigned u = __float_as_uint(x);
  return (unsigned short)((u + 0x7FFF + ((u >> 16) & 1)) >> 16);
}

// ---- fp8 e4m3 (OCP) helpers ----
__device__ __forceinline__ float fp8_dec1(unsigned v){
  unsigned s = (v >> 7) & 1, e = (v >> 3) & 15, m = v & 7;
  float r = e ? __uint_as_float(((e + 120) << 23) | (m << 20))
              : (float)m * 0.001953125f;
  return s ? -r : r;
}
__device__ __forceinline__ unsigned fp8_enc1(float x){
  float a = fabsf(x);
  if (a > 448.f) a = 448.f;
  unsigned sgn = (__float_as_uint(x) >> 31) << 7;
  unsigned res;
  if (a < 0.015625f){
    res = (unsigned)__float2int_rn(a * 512.f);
    if (res > 7) res = 8;
    if (res == 8) res = 0x08;
  } else {
    unsigned ab = __float_as_uint(a);
    unsigned r = ab + 0x0007FFFF + ((ab >> 20) & 1);
    int e = (int)(r >> 23) - 127;
    unsigned m = (r >> 20) & 7;
    if (e > 8){ e = 8; m = 6; }
    res = ((unsigned)(e + 7) << 3) | m;
  }
  return res | sgn;
}

__device__ __forceinline__ void fp8x4_acc(unsigned w, float* a){
#if __has_builtin(__builtin_amdgcn_cvt_pk_f32_fp8)
  f32x2 p0 = __builtin_amdgcn_cvt_pk_f32_fp8((int)w, false);
  f32x2 p1 = __builtin_amdgcn_cvt_pk_f32_fp8((int)w, true);
  a[0] += p0.x; a[1] += p0.y; a[2] += p1.x; a[3] += p1.y;
#else
  a[0] += fp8_dec1(w & 255);
  a[1] += fp8_dec1((w >> 8) & 255);
  a[2] += fp8_dec1((w >> 16) & 255);
  a[3] += fp8_dec1(w >> 24);
#endif
}
__device__ __forceinline__ unsigned fp8x4_enc(float x0, float x1, float x2, float x3){
#if __has_builtin(__builtin_amdgcn_cvt_pk_fp8_f32)
  int v = 0;
  v = __builtin_amdgcn_cvt_pk_fp8_f32(x0, x1, v, false);
  v = __builtin_amdgcn_cvt_pk_fp8_f32(x2, x3, v, true);
  return (unsigned)v;
#else
  return fp8_enc1(x0) | (fp8_enc1(x1) << 8) | (fp8_enc1(x2) << 16) | (fp8_enc1(x3) << 24);
#endif
}

// ---------------- CSR build (all 3 graphs in one pass-set) ----------------
__global__ __launch_bounds__(256) void k_hist1(const int* __restrict__ k0, const int* __restrict__ k1,
                                               const int* __restrict__ k2, int* __restrict__ hist){
  __shared__ int lh[400];
  const int g = blockIdx.y;
  const int n  = (g == 0) ? EGG : EGDA;
  const int B1 = (g == 1) ? B1D : B1G;
  const int bb = (g == 0) ? 0 : (g == 1 ? B1G : B1G + B1D);
  const int* key = (g == 0) ? k0 : (g == 1 ? k1 : k2);
  for (int t = threadIdx.x; t < B1; t += 256) lh[t] = 0;
  __syncthreads();
  for (int i = blockIdx.x*blockDim.x + threadIdx.x; i < n; i += gridDim.x*blockDim.x)
    atomicAdd(&lh[key[i] >> 7], 1);
  __syncthreads();
  for (int t = threadIdx.x; t < B1; t += 256){
    int c = lh[t];
    if (c) atomicAdd(&hist[bb + t], c);
  }
}

__global__ __launch_bounds__(1024) void k_exscan(const int* __restrict__ cnt,
                                                 int* __restrict__ ptr, int* __restrict__ cur, int n){
  __shared__ int wsum[16];
  __shared__ int carry;
  const int tid = threadIdx.x, lane = tid & 63, wid = tid >> 6;
  if (tid == 0) carry = 0;
  __syncthreads();
  for (int base = 0; base < n; base += 4096){
    int i0 = base + tid*4;
    int4 v = {0,0,0,0};
    if (i0 < n) v = *(const int4*)(cnt + i0);
    int tsum = v.x + v.y + v.z + v.w;
    int x = tsum;
    #pragma unroll
    for (int off = 1; off < 64; off <<= 1){
      int t = __shfl_up(x, off);
      if (lane >= off) x += t;
    }
    if (lane == 63) wsum[wid] = x;
    __syncthreads();
    if (wid == 0 && lane < 16){
      int w = wsum[lane];
      #pragma unroll
      for (int off = 1; off < 16; off <<= 1){
        int t = __shfl_up(w, off);
        if (lane >= off) w += t;
      }
      wsum[lane] = w;
    }
    __syncthreads();
    int waveoff = wid ? wsum[wid-1] : 0;
    if (i0 < n){
      int ex = carry + waveoff + x - tsum;
      int4 o;
      o.x = ex; o.y = ex + v.x; o.z = o.y + v.y; o.w = o.z + v.z;
      *(int4*)(ptr + i0) = o;
      *(int4*)(cur + i0) = o;
    }
    int total = wsum[15];
    __syncthreads();
    if (tid == 0) carry += total;
    __syncthreads();
  }
  if (tid == 0) ptr[n] = carry;
}

__global__ __launch_bounds__(256) void k_scatter1(const int* __restrict__ k0, const int* __restrict__ v0,
                                                  const int* __restrict__ k1, const int* __restrict__ v1,
                                                  int* __restrict__ gcur, unsigned* __restrict__ pk){
  __shared__ int lh[400];
  __shared__ int base[400];
  const int g = blockIdx.y;
  const int n  = (g == 0) ? EGG : EGDA;
  const int B1 = (g == 1) ? B1D : B1G;
  const int bb = (g == 0) ? 0 : (g == 1 ? B1G : B1G + B1D);
  const int* key = (g == 0) ? k0 : (g == 1 ? k1 : v1);
  const int* val = (g == 0) ? v0 : (g == 1 ? v1 : k1);
  const int tid = threadIdx.x;
  const int chunk0 = blockIdx.x*4096;
  if (chunk0 >= n) return;
  for (int t = tid; t < B1; t += 256) lh[t] = 0;
  __syncthreads();
  int kd[16], vv[16];
  #pragma unroll
  for (int it = 0; it < 16; ++it){
    int i = chunk0 + it*256 + tid;
    int k = -1, v = 0;
    if (i < n){ k = key[i]; v = val[i]; atomicAdd(&lh[k >> 7], 1); }
    kd[it] = k; vv[it] = v;
  }
  __syncthreads();
  for (int t = tid; t < B1; t += 256){
    int c = lh[t];
    base[t] = c ? atomicAdd(&gcur[bb + t], c) : 0;
    lh[t] = 0;
  }
  __syncthreads();
  #pragma unroll
  for (int it = 0; it < 16; ++it){
    int k = kd[it];
    if (k >= 0){
      int b = k >> 7;
      int p = base[b] + atomicAdd(&lh[b], 1);
      pk[p] = ((unsigned)(k & 127) << 17) | (unsigned)vv[it];
    }
  }
}

__global__ __launch_bounds__(256) void k_csr2(const unsigned* __restrict__ pk,
                                              const int* __restrict__ gbase,
                                              int* __restrict__ ptr_all, int* __restrict__ col){
  __shared__ int lh[128];
  __shared__ int cur[128];
  __shared__ int sh0;
  const int b = blockIdx.x, tid = threadIdx.x;
  int lb, pbase, Ngr, bend;
  if (b < B1G)            { lb = b;             pbase = PB0; Ngr = NG; bend = B1G; }
  else if (b < B1G + B1D) { lb = b - B1G;       pbase = PB1; Ngr = ND; bend = B1G + B1D; }
  else                    { lb = b - B1G - B1D; pbase = PB2; Ngr = NG; bend = TB; }
  const int s = gbase[b], e = gbase[b+1];
  if (tid < 128) lh[tid] = 0;
  __syncthreads();
  for (int i = s + tid; i < e; i += 256)
    atomicAdd(&lh[(pk[i] >> 17) & 127], 1);
  __syncthreads();
  int lane = tid & 63;
  int v = 0, x = 0;
  if (tid < 128){
    v = lh[tid]; x = v;
    #pragma unroll
    for (int o = 1; o < 64; o <<= 1){
      int t = __shfl_up(x, o);
      if (lane >= o) x += t;
    }
    if (tid == 63) sh0 = x;
  }
  __syncthreads();
  if (tid < 128){
    int excl = x - v + (tid >= 64 ? sh0 : 0);
    cur[tid] = s + excl;
    int loc = (lb << 7) + tid;
    if (loc < Ngr) ptr_all[pbase + loc] = s + excl;
  }
  __syncthreads();
  for (int i = s + tid; i < e; i += 256){
    unsigned p = pk[i];
    int dl = (p >> 17) & 127;
    int pos = atomicAdd(&cur[dl], 1);
    col[pos] = (int)(p & 0x1FFFFu);
  }
  if (lb == 0 && tid == 0) ptr_all[pbase + Ngr] = gbase[bend];
}

// ---------------- prep: weight compose + bias + f2b/f2fp8, one dispatch ----------------
#define PREP_F2B_BLOCKS (((NG+ND)*32)/256)   // 8750
__global__ __launch_bounds__(256) void k_prep(
    const float* __restrict__ Wd1, const float* __restrict__ Ws1, const float* __restrict__ Wu1,
    const float* __restrict__ Wd2, const float* __restrict__ Ws2, const float* __restrict__ Wu2,
    const float* __restrict__ bd1, const float* __restrict__ bs1, const float* __restrict__ bu1,
    const float* __restrict__ bd2, const float* __restrict__ bs2, const float* __restrict__ bu2,
    float* __restrict__ AB, float* __restrict__ cv,
    const float* __restrict__ Xg, const float* __restrict__ Xd,
    unsigned short* __restrict__ Yg, unsigned short* __restrict__ Yd,
    unsigned* __restrict__ Yg8, unsigned* __restrict__ Yd8){
  const int b = blockIdx.x, tid = threadIdx.x;
  if (b < 768){
    int idx = b*256 + tid;
    int layer = idx / 98304;
    int r0 = idx - layer*98304;
    int mat = r0 >> 14;
    int r   = (r0 >> 7) & 127;
    int c   = r0 & 127;
    int i   = mat >> 1;
    int isB = mat & 1;
    const float* Wd = layer ? Wd2 : Wd1;
    const float* Ws = layer ? Ws2 : Ws1;
    const float* Wu = layer ? Wu2 : Wu1;
    const float* P = (isB ? Ws : Wd) + i*16384 + r*128;
    const float* Q = Wu + i*32768 + (isB ? 16384 : 0) + c;
    float s = 0.f;
    for (int h = 0; h < 128; ++h) s += P[h] * Q[h*128];
    AB[idx] = s;
  } else if (b < 771){
    int idx = (b - 768)*256 + tid;
    if (idx >= 768) return;
    int layer = idx / 384;
    int r = idx - layer*384;
    int i = r >> 7, h = r & 127;
    const float* bd = layer ? bd2 : bd1;
    const float* bs = layer ? bs2 : bs1;
    const float* bu = layer ? bu2 : bu1;
    const float* Wu = layer ? Wu2 : Wu1;
    float s = bu[i*128 + h];
    const float* Ut = Wu + i*32768 + h;
    const float* Ub = Ut + 16384;
    for (int k = 0; k < 128; ++k)
      s += bd[i*128 + k] * Ut[k*128] + bs[i*128 + k] * Ub[k*128];
    cv[idx] = s;
  } else {
    int idx = (b - 771)*256 + tid;
    const int GQ = NG*32;
    const float* X; unsigned short* Y; unsigned* Y8; int i;
    if (idx < GQ){ X = Xg; Y = Yg; Y8 = Yg8; i = idx; }
    else         { X = Xd; Y = Yd; Y8 = Yd8; i = idx - GQ; }
    float4 v = ((const float4*)X)[i];
    ushort4 o;
    o.x = f2b(v.x); o.y = f2b(v.y); o.z = f2b(v.z); o.w = f2b(v.w);
    ((ushort4*)Y)[i] = o;
    Y8[i] = fp8x4_enc(v.x, v.y, v.z, v.w);
  }
}

// pack B-fragment order (hi-only), both layers + gene/dis in one kernel
__global__ __launch_bounds__(256) void k_pack(const float* __restrict__ AB, const float* __restrict__ cv,
                                              bf16* __restrict__ Wg1, bf16* __restrict__ Wd1p,
                                              bf16* __restrict__ Wg2, bf16* __restrict__ Wd2p,
                                              float* __restrict__ cg1, float* __restrict__ cd1,
                                              float* __restrict__ cg2, float* __restrict__ cd2){
  int idx = blockIdx.x*256 + threadIdx.x;
  int layer = idx / 81920;
  int rem = idx - layer*81920;
  const float* ABl = AB + layer*98304;
  const float* cvl = cv + layer*384;
  if (rem < 49152){
    int n0  = rem / 6144;
    int r2  = rem - n0*6144;
    int ks  = r2 >> 9;
    int lane = (r2 >> 3) & 63;
    int j   = r2 & 7;
    int k   = ks*32 + (lane >> 4)*8 + j;
    int c   = n0*16 + (lane & 15);
    float v;
    if      (k < 128) v = 0.5f*(ABl[0*16384 + k*128 + c] + ABl[4*16384 + k*128 + c]);
    else if (k < 256) v = 0.5f* ABl[1*16384 + (k-128)*128 + c];
    else              v = 0.5f* ABl[5*16384 + (k-256)*128 + c];
    bf16* W = layer ? Wg2 : Wg1;
    ((unsigned short*)W)[rem] = f2b(v);
    if (rem < 128){
      float* cg = layer ? cg2 : cg1;
      cg[rem] = 0.5f*(cvl[rem] + cvl[256 + rem]);
    }
  } else {
    int d = rem - 49152;
    int n0  = d >> 12;
    int ks  = (d >> 9) & 7;
    int lane = (d >> 3) & 63;
    int j   = d & 7;
    int k   = ks*32 + (lane >> 4)*8 + j;
    int c   = n0*16 + (lane & 15);
    float v = (k < 128) ? ABl[2*16384 + k*128 + c] : ABl[3*16384 + (k-128)*128 + c];
    bf16* W = layer ? Wd2p : Wd1p;
    ((unsigned short*)W)[d] = f2b(v);
    if (d < 128){
      float* cd = layer ? cd2 : cd1;
      cd[d] = cvl[128 + d];
    }
  }
}

// ---------------- fused layer: per-block agg (LDS) -> MFMA GEMM -> (BN partials) ----------------
#define GBG32 ((NG+31)/32)
#define GBD32 ((ND+31)/32)

template<int KS, int DO_BN>
__device__ __forceinline__ void layer_body(
    const bf16* __restrict__ X0,
    const unsigned* __restrict__ S8a, const unsigned* __restrict__ S8b,
    const int* __restrict__ ptrA, const int* __restrict__ ptrB,
    const int* __restrict__ col,
    const bf16* __restrict__ Wp, const float* __restrict__ cvec,
    unsigned short* __restrict__ Out, float* __restrict__ bnglob,
    int M, int blk, short (*lds_agg)[32][128], float* bnacc){
  const int tid = threadIdx.x;
  const int row0 = blk*32;

  // ---- agg phase: quarter-wave per (row, graph) task; identical math to old k_agg ----
  {
    const int qw = tid >> 4, lane = tid & 15;
    const int loff = lane*2;
    const int NT = (KS == 12) ? 64 : 32;
    for (int t = qw; t < NT; t += 16){
      int lr  = (KS == 12) ? (t >> 1) : t;
      int row = row0 + lr;
      if (row < M){
        int g = (KS == 12) ? (t & 1) : 0;
        const unsigned* X8 = g ? S8b : S8a;
        const int* ptr = g ? ptrB : ptrA;
        int s = ptr[row], e = ptr[row+1];
        float a[8];
        #pragma unroll
        for (int j = 0; j < 8; ++j) a[j] = 0.f;
        int i = s;
        for (; i + 4 <= e; i += 4){
          uint2 u0 = *(const uint2*)(X8 + (size_t)col[i  ]*32 + loff);
          uint2 u1 = *(const uint2*)(X8 + (size_t)col[i+1]*32 + loff);
          uint2 u2 = *(const uint2*)(X8 + (size_t)col[i+2]*32 + loff);
          uint2 u3 = *(const uint2*)(X8 + (size_t)col[i+3]*32 + loff);
          fp8x4_acc(u0.x, a);     fp8x4_acc(u0.y, a+4);
          fp8x4_acc(u1.x, a);     fp8x4_acc(u1.y, a+4);
          fp8x4_acc(u2.x, a);     fp8x4_acc(u2.y, a+4);
          fp8x4_acc(u3.x, a);     fp8x4_acc(u3.y, a+4);
        }
        for (; i < e; ++i){
          uint2 u = *(const uint2*)(X8 + (size_t)col[i]*32 + loff);
          fp8x4_acc(u.x, a);      fp8x4_acc(u.y, a+4);
        }
        float inv = 1.f / fmaxf((float)(e - s), 1.f);
        bf16x8 o;
        #pragma unroll
        for (int j = 0; j < 8; ++j) o[j] = (short)f2b(a[j]*inv);
        *(bf16x8*)&lds_agg[g][lr][lane*8] = o;
      }
    }
  }
  __syncthreads();

  // ---- GEMM phase: identical to old gemm_body<KS>, X1/X2 from LDS ----
  const int wave = tid >> 6, lane = tid & 63;
  const int lrow = lane & 15, quad = lane >> 4;
  f32x4 acc[2][2];
  #pragma unroll
  for (int p = 0; p < 2; ++p)
    #pragma unroll
    for (int t = 0; t < 2; ++t) acc[p][t] = 0.0f;
  const bf16x8* wp = (const bf16x8*)Wp;
  const int f00 = (2*wave*KS)*64 + lane;
  #pragma unroll
  for (int ks = 0; ks < KS; ++ks){
    const int kk = (ks & 3)*32 + quad*8;
    bf16x8 a[2];
    #pragma unroll
    for (int t = 0; t < 2; ++t){
      int ar = row0 + t*16 + lrow; if (ar > M-1) ar = M-1;
      if (ks < 4) a[t] = *(const bf16x8*)(X0 + (size_t)ar*DH + kk);
      else        a[t] = *(const bf16x8*)&lds_agg[(ks >> 2) - 1][ar - row0][kk];
    }
    bf16x8 b0 = wp[f00 + ks*64];
    bf16x8 b1 = wp[f00 + (KS + ks)*64];
    #pragma unroll
    for (int t = 0; t < 2; ++t){
      acc[0][t] = __builtin_amdgcn_mfma_f32_16x16x32_bf16(a[t], b0, acc[0][t], 0, 0, 0);
      acc[1][t] = __builtin_amdgcn_mfma_f32_16x16x32_bf16(a[t], b1, acc[1][t], 0, 0, 0);
    }
  }

  // ---- epilogue: store + optional BN partial sums (from the rounded bf16 values) ----
  #pragma unroll
  for (int p = 0; p < 2; ++p){
    int c = (2*wave + p)*16 + lrow;
    float cb = cvec[c];
    float sl = 0.f, ql = 0.f;
    #pragma unroll
    for (int t = 0; t < 2; ++t){
      #pragma unroll
      for (int r = 0; r < 4; ++r){
        int row = row0 + t*16 + quad*4 + r;
        if (row < M){
          unsigned short us = f2b(acc[p][t][r] + cb);
          Out[(size_t)row*DH + c] = us;
          if (DO_BN){
            float f = bf2f((short)us);
            sl += f; ql += f*f;
          }
        }
      }
    }
    if (DO_BN){
      atomicAdd(&bnacc[c], sl);
      atomicAdd(&bnacc[128 + c], ql);
    }
  }
  if (DO_BN){
    __syncthreads();
    atomicAdd(&bnglob[tid], bnacc[tid]);
  }
}

template<int DO_BN>
__global__ __launch_bounds__(256) void k_layer(
    const bf16* __restrict__ Xg, const bf16* __restrict__ Xd,
    const unsigned* __restrict__ xg8, const unsigned* __restrict__ xd8,
    const int* __restrict__ ptr_all, const int* __restrict__ col,
    const bf16* __restrict__ Wg, const float* __restrict__ cg, unsigned short* __restrict__ Og,
    const bf16* __restrict__ Wd, const float* __restrict__ cd, unsigned short* __restrict__ Od,
    float* __restrict__ bnsum){
  __shared__ short lds_agg[2][32][128];
  __shared__ float bnacc[256];
  if (DO_BN) bnacc[threadIdx.x] = 0.f;     // agg-phase __syncthreads covers visibility
  if ((int)blockIdx.x < GBG32)
    layer_body<12, DO_BN>(Xg, xg8, xd8, ptr_all + PB0, ptr_all + PB2, col,
                          Wg, cg, Og, bnsum, NG, blockIdx.x, lds_agg, bnacc);
  else
    layer_body<8, DO_BN>(Xd, xg8, xg8, ptr_all + PB1, ptr_all + PB1, col,
                         Wd, cd, Od, bnsum + 256, ND, blockIdx.x - GBG32, lds_agg, bnacc);
}

// BN + LeakyReLU, both matrices; writes bf16 + fp8 copies
__global__ __launch_bounds__(256) void k_bn_apply(const bf16* __restrict__ Xgb, const bf16* __restrict__ Xdb,
    const float* __restrict__ sums, const float* __restrict__ gamma, const float* __restrict__ beta,
    unsigned short* __restrict__ Yg, unsigned short* __restrict__ Yd,
    uint2* __restrict__ Yg8, uint2* __restrict__ Yd8){
  __shared__ float sc[256], sb[256];
  int tid = threadIdx.x;
  {
    int g = tid >> 7, c = tid & 127;
    float invN = g ? (1.f/ND) : (1.f/NG);
    const float* sm = sums + g*256;
    float m = sm[c]*invN;
    float v = sm[128 + c]*invN - m*m;
    float s = rsqrtf(v + 1e-5f) * gamma[g*128 + c];
    sc[tid] = s;
    sb[tid] = beta[g*128 + c] - m*s;
  }
  __syncthreads();
  const int GT = NG*16;
  const int TOT = GT + ND*16;
  for (int idx = blockIdx.x*256 + tid; idx < TOT; idx += gridDim.x*256){
    const bf16x8* src; bf16x8* dst; uint2* dst8; int i, cb;
    if (idx < GT){ src = (const bf16x8*)Xgb; dst = (bf16x8*)Yg; dst8 = Yg8; i = idx; cb = 0; }
    else         { src = (const bf16x8*)Xdb; dst = (bf16x8*)Yd; dst8 = Yd8; i = idx - GT; cb = 128; }
    bf16x8 v = src[i];
    int c = cb + (i & 15)*8;
    float y[8];
    bf16x8 o;
    #pragma unroll
    for (int j = 0; j < 8; ++j){
      float t = bf2f(v[j])*sc[c+j] + sb[c+j];
      t = t >= 0.f ? t : 0.01f*t;
      y[j] = t;
      o[j] = (short)f2b(t);
    }
    dst[i] = o;
    uint2 p;
    p.x = fp8x4_enc(y[0], y[1], y[2], y[3]);
    p.y = fp8x4_enc(y[4], y[5], y[6], y[7]);
    dst8[i] = p;
  }
}

// ---------------- decoder: 2 edges per quarter-wave (bf16 in) ----------------
__global__ __launch_bounds__(256) void k_decode(const bf16* __restrict__ G, const bf16* __restrict__ Dd,
    const int* __restrict__ ls, const int* __restrict__ ld, float* __restrict__ out, int E){
  int p = (blockIdx.x*256 + threadIdx.x) >> 4;
  int lane = threadIdx.x & 15;
  int e0 = p*2, e1 = p*2 + 1;
  if (e0 >= E) return;
  int a0 = ls[e0], b0 = ld[e0];
  int a1 = ls[e1], b1 = ld[e1];
  const size_t loff = (size_t)lane*8;
  bf16x8 g0 = *(const bf16x8*)(G  + (size_t)a0*DH + loff);
  bf16x8 d0 = *(const bf16x8*)(Dd + (size_t)b0*DH + loff);
  bf16x8 g1 = *(const bf16x8*)(G  + (size_t)a1*DH + loff);
  bf16x8 d1 = *(const bf16x8*)(Dd + (size_t)b1*DH + loff);
  float s0 = 0.f, s1 = 0.f;
  #pragma unroll
  for (int j = 0; j < 8; ++j){
    s0 += bf2f(g0[j])*bf2f(d0[j]);
    s1 += bf2f(g1[j])*bf2f(d1[j]);
  }
  #pragma unroll
  for (int off = 8; off; off >>= 1){
    s0 += __shfl_down(s0, off, 16);
    s1 += __shfl_down(s1, off, 16);
  }
  if (lane == 0){ out[e0] = s0; out[e1] = s1; }
}

// ---------------- launch ----------------
extern "C" void kernel_launch(void* const* d_in, const int* in_sizes, int n_in,
                              void* d_out, int out_size, void* d_ws, size_t ws_size,
                              hipStream_t stream){
  const float* x_gene = (const float*)d_in[0];
  const float* x_dis  = (const float*)d_in[1];
  const float* Wd1 = (const float*)d_in[2];
  const float* Ws1 = (const float*)d_in[3];
  const float* Wu1 = (const float*)d_in[4];
  const float* bd1 = (const float*)d_in[5];
  const float* bs1 = (const float*)d_in[6];
  const float* bu1 = (const float*)d_in[7];
  const float* Wd2 = (const float*)d_in[8];
  const float* Ws2 = (const float*)d_in[9];
  const float* Wu2 = (const float*)d_in[10];
  const float* bd2 = (const float*)d_in[11];
  const float* bs2 = (const float*)d_in[12];
  const float* bu2 = (const float*)d_in[13];
  const float* bng = (const float*)d_in[14];
  const float* bnb = (const float*)d_in[15];
  const int* gg_src  = (const int*)d_in[16];
  const int* gg_dst  = (const int*)d_in[17];
  const int* gda_src = (const int*)d_in[18];
  const int* gda_dst = (const int*)d_in[19];
  const int* lsrc = (const int*)d_in[20];
  const int* ldst = (const int*)d_in[21];

  char* ws = (char*)d_ws;
  size_t off = 0;
  auto alloc = [&](size_t bytes)->void*{
    void* p = ws + off; off += (bytes + 255) & ~(size_t)255; return p;
  };
  int* hist    = (int*)alloc(960*4);
  float* bnsum = (float*)alloc(2*256*4);
  int* gbase   = (int*)alloc(960*4);
  int* gcur    = (int*)alloc(960*4);
  int* ptr_all = (int*)alloc((size_t)(NG+1+ND+1+NG+1)*4);
  int* col     = (int*)alloc((size_t)(EGG+2*EGDA)*4);
  unsigned* pk = (unsigned*)alloc((size_t)(EGG+2*EGDA)*4);
  float* AB  = (float*)alloc(2*98304*4);
  float* cv  = (float*)alloc(2*384*4);
  float* cg1 = (float*)alloc(128*4);
  float* cd1 = (float*)alloc(128*4);
  float* cg2 = (float*)alloc(128*4);
  float* cd2 = (float*)alloc(128*4);
  bf16* Wg1  = (bf16*)alloc(49152*2);
  bf16* Wp1  = (bf16*)alloc(32768*2);
  bf16* Wg2  = (bf16*)alloc(49152*2);
  bf16* Wp2  = (bf16*)alloc(32768*2);
  bf16* xgb  = (bf16*)alloc((size_t)NG*DH*2);
  bf16* xdb  = (bf16*)alloc((size_t)ND*DH*2);
  unsigned* xg8  = (unsigned*)alloc((size_t)NG*DH);
  unsigned* xd8  = (unsigned*)alloc((size_t)ND*DH);
  unsigned* Xg28 = (unsigned*)alloc((size_t)NG*DH);
  unsigned* Xd28 = (unsigned*)alloc((size_t)ND*DH);
  bf16* Xg2b = (bf16*)alloc((size_t)NG*DH*2);
  bf16* Xd2b = (bf16*)alloc((size_t)ND*DH*2);
  bf16* outgb = (bf16*)alloc((size_t)NG*DH*2);
  bf16* outdb = (bf16*)alloc((size_t)ND*DH*2);

  hipMemsetAsync(hist, 0, 960*4 + 512*4, stream);

  // --- CSR build: all 3 graphs ---
  {
    dim3 gh(96, 3);
    k_hist1<<<gh,256,0,stream>>>(gg_dst, gda_dst, gda_src, hist);
    k_exscan<<<1,1024,0,stream>>>(hist, gbase, gcur, TBP);
    dim3 gs(196, 3);
    k_scatter1<<<gs,256,0,stream>>>(gg_dst, gg_src, gda_dst, gda_src, gcur, pk);
    k_csr2<<<TB,256,0,stream>>>(pk, gbase, ptr_all, col);
  }

  // --- prep: weight compose + bias + f2b/f2fp8 (one dispatch) ---
  k_prep<<<771 + PREP_F2B_BLOCKS,256,0,stream>>>(
      Wd1, Ws1, Wu1, Wd2, Ws2, Wu2, bd1, bs1, bu1, bd2, bs2, bu2,
      AB, cv, x_gene, x_dis, (unsigned short*)xgb, (unsigned short*)xdb, xg8, xd8);
  k_pack<<<640,256,0,stream>>>(AB, cv, Wg1, Wp1, Wg2, Wp2, cg1, cd1, cg2, cd2);

  // --- layer 1 (fused agg+gemm+bn-partials) ---
  k_layer<1><<<GBG32+GBD32,256,0,stream>>>(xgb, xdb, xg8, xd8, ptr_all, col,
                                           Wg1, cg1, (unsigned short*)outgb,
                                           Wp1, cd1, (unsigned short*)outdb, bnsum);
  k_bn_apply<<<1024,256,0,stream>>>(outgb, outdb, bnsum, bng, bnb,
                                    (unsigned short*)Xg2b, (unsigned short*)Xd2b,
                                    (uint2*)Xg28, (uint2*)Xd28);

  // --- layer 2 (fused agg+gemm) ---
  k_layer<0><<<GBG32+GBD32,256,0,stream>>>(Xg2b, Xd2b, Xg28, Xd28, ptr_all, col,
                                           Wg2, cg2, (unsigned short*)outgb,
                                           Wp2, cd2, (unsigned short*)outdb, bnsum);

  // --- decoder ---
  k_decode<<<ELAB*16/2/256,256,0,stream>>>(outgb, outdb, lsrc, ldst, (float*)d_out, ELAB);
}

// Round 13
// 352.717 us; speedup vs baseline: 1.0084x; 1.0084x over previous
//
#include <hip/hip_runtime.h>
#include <hip/hip_bf16.h>
#include <cstddef>

#define NG   50000
#define ND   20000
#define DH   128
#define EGG  800000
#define EGDA 400000
#define ELAB 200000

#define B1G 391
#define B1D 157
#define TB  939
#define TBP 940
#define PB0 0
#define PB1 (NG+1)
#define PB2 (NG+1+ND+1)

// padded LDS row stride (shorts): 136 -> 272B -> 68 dwords == 4 mod 32 banks
#define LSTR 136

typedef __hip_bfloat16  bf16;
typedef __attribute__((ext_vector_type(8))) short bf16x8;
typedef __attribute__((ext_vector_type(4))) float f32x4;
typedef __attribute__((ext_vector_type(2))) float f32x2;

__device__ __forceinline__ float bf2f(short s){
  return __uint_as_float(((unsigned)(unsigned short)s) << 16);
}
__device__ __forceinline__ unsigned short f2b(float x){
  unsigned u = __float_as_uint(x);
  return (unsigned short)((u + 0x7FFF + ((u >> 16) & 1)) >> 16);
}

// ---- fp8 e4m3 (OCP) helpers ----
__device__ __forceinline__ float fp8_dec1(unsigned v){
  unsigned s = (v >> 7) & 1, e = (v >> 3) & 15, m = v & 7;
  float r = e ? __uint_as_float(((e + 120) << 23) | (m << 20))
              : (float)m * 0.001953125f;
  return s ? -r : r;
}
__device__ __forceinline__ unsigned fp8_enc1(float x){
  float a = fabsf(x);
  if (a > 448.f) a = 448.f;
  unsigned sgn = (__float_as_uint(x) >> 31) << 7;
  unsigned res;
  if (a < 0.015625f){
    res = (unsigned)__float2int_rn(a * 512.f);
    if (res > 7) res = 8;
    if (res == 8) res = 0x08;
  } else {
    unsigned ab = __float_as_uint(a);
    unsigned r = ab + 0x0007FFFF + ((ab >> 20) & 1);
    int e = (int)(r >> 23) - 127;
    unsigned m = (r >> 20) & 7;
    if (e > 8){ e = 8; m = 6; }
    res = ((unsigned)(e + 7) << 3) | m;
  }
  return res | sgn;
}

__device__ __forceinline__ void fp8x4_acc(unsigned w, float* a){
#if __has_builtin(__builtin_amdgcn_cvt_pk_f32_fp8)
  f32x2 p0 = __builtin_amdgcn_cvt_pk_f32_fp8((int)w, false);
  f32x2 p1 = __builtin_amdgcn_cvt_pk_f32_fp8((int)w, true);
  a[0] += p0.x; a[1] += p0.y; a[2] += p1.x; a[3] += p1.y;
#else
  a[0] += fp8_dec1(w & 255);
  a[1] += fp8_dec1((w >> 8) & 255);
  a[2] += fp8_dec1((w >> 16) & 255);
  a[3] += fp8_dec1(w >> 24);
#endif
}
__device__ __forceinline__ unsigned fp8x4_enc(float x0, float x1, float x2, float x3){
#if __has_builtin(__builtin_amdgcn_cvt_pk_fp8_f32)
  int v = 0;
  v = __builtin_amdgcn_cvt_pk_fp8_f32(x0, x1, v, false);
  v = __builtin_amdgcn_cvt_pk_fp8_f32(x2, x3, v, true);
  return (unsigned)v;
#else
  return fp8_enc1(x0) | (fp8_enc1(x1) << 8) | (fp8_enc1(x2) << 16) | (fp8_enc1(x3) << 24);
#endif
}

// ---------------- CSR build (all 3 graphs in one pass-set) ----------------
__global__ __launch_bounds__(256) void k_hist1(const int* __restrict__ k0, const int* __restrict__ k1,
                                               const int* __restrict__ k2, int* __restrict__ hist){
  __shared__ int lh[400];
  const int g = blockIdx.y;
  const int n  = (g == 0) ? EGG : EGDA;
  const int B1 = (g == 1) ? B1D : B1G;
  const int bb = (g == 0) ? 0 : (g == 1 ? B1G : B1G + B1D);
  const int* key = (g == 0) ? k0 : (g == 1 ? k1 : k2);
  for (int t = threadIdx.x; t < B1; t += 256) lh[t] = 0;
  __syncthreads();
  for (int i = blockIdx.x*blockDim.x + threadIdx.x; i < n; i += gridDim.x*blockDim.x)
    atomicAdd(&lh[key[i] >> 7], 1);
  __syncthreads();
  for (int t = threadIdx.x; t < B1; t += 256){
    int c = lh[t];
    if (c) atomicAdd(&hist[bb + t], c);
  }
}

__global__ __launch_bounds__(1024) void k_exscan(const int* __restrict__ cnt,
                                                 int* __restrict__ ptr, int* __restrict__ cur, int n){
  __shared__ int wsum[16];
  __shared__ int carry;
  const int tid = threadIdx.x, lane = tid & 63, wid = tid >> 6;
  if (tid == 0) carry = 0;
  __syncthreads();
  for (int base = 0; base < n; base += 4096){
    int i0 = base + tid*4;
    int4 v = {0,0,0,0};
    if (i0 < n) v = *(const int4*)(cnt + i0);
    int tsum = v.x + v.y + v.z + v.w;
    int x = tsum;
    #pragma unroll
    for (int off = 1; off < 64; off <<= 1){
      int t = __shfl_up(x, off);
      if (lane >= off) x += t;
    }
    if (lane == 63) wsum[wid] = x;
    __syncthreads();
    if (wid == 0 && lane < 16){
      int w = wsum[lane];
      #pragma unroll
      for (int off = 1; off < 16; off <<= 1){
        int t = __shfl_up(w, off);
        if (lane >= off) w += t;
      }
      wsum[lane] = w;
    }
    __syncthreads();
    int waveoff = wid ? wsum[wid-1] : 0;
    if (i0 < n){
      int ex = carry + waveoff + x - tsum;
      int4 o;
      o.x = ex; o.y = ex + v.x; o.z = o.y + v.y; o.w = o.z + v.z;
      *(int4*)(ptr + i0) = o;
      *(int4*)(cur + i0) = o;
    }
    int total = wsum[15];
    __syncthreads();
    if (tid == 0) carry += total;
    __syncthreads();
  }
  if (tid == 0) ptr[n] = carry;
}

__global__ __launch_bounds__(256) void k_scatter1(const int* __restrict__ k0, const int* __restrict__ v0,
                                                  const int* __restrict__ k1, const int* __restrict__ v1,
                                                  int* __restrict__ gcur, unsigned* __restrict__ pk){
  __shared__ int lh[400];
  __shared__ int base[400];
  const int g = blockIdx.y;
  const int n  = (g == 0) ? EGG : EGDA;
  const int B1 = (g == 1) ? B1D : B1G;
  const int bb = (g == 0) ? 0 : (g == 1 ? B1G : B1G + B1D);
  const int* key = (g == 0) ? k0 : (g == 1 ? k1 : v1);
  const int* val = (g == 0) ? v0 : (g == 1 ? v1 : k1);
  const int tid = threadIdx.x;
  const int chunk0 = blockIdx.x*4096;
  if (chunk0 >= n) return;
  for (int t = tid; t < B1; t += 256) lh[t] = 0;
  __syncthreads();
  int kd[16], vv[16];
  #pragma unroll
  for (int it = 0; it < 16; ++it){
    int i = chunk0 + it*256 + tid;
    int k = -1, v = 0;
    if (i < n){ k = key[i]; v = val[i]; atomicAdd(&lh[k >> 7], 1); }
    kd[it] = k; vv[it] = v;
  }
  __syncthreads();
  for (int t = tid; t < B1; t += 256){
    int c = lh[t];
    base[t] = c ? atomicAdd(&gcur[bb + t], c) : 0;
    lh[t] = 0;
  }
  __syncthreads();
  #pragma unroll
  for (int it = 0; it < 16; ++it){
    int k = kd[it];
    if (k >= 0){
      int b = k >> 7;
      int p = base[b] + atomicAdd(&lh[b], 1);
      pk[p] = ((unsigned)(k & 127) << 17) | (unsigned)vv[it];
    }
  }
}

__global__ __launch_bounds__(256) void k_csr2(const unsigned* __restrict__ pk,
                                              const int* __restrict__ gbase,
                                              int* __restrict__ ptr_all, int* __restrict__ col){
  __shared__ int lh[128];
  __shared__ int cur[128];
  __shared__ int sh0;
  const int b = blockIdx.x, tid = threadIdx.x;
  int lb, pbase, Ngr, bend;
  if (b < B1G)            { lb = b;             pbase = PB0; Ngr = NG; bend = B1G; }
  else if (b < B1G + B1D) { lb = b - B1G;       pbase = PB1; Ngr = ND; bend = B1G + B1D; }
  else                    { lb = b - B1G - B1D; pbase = PB2; Ngr = NG; bend = TB; }
  const int s = gbase[b], e = gbase[b+1];
  if (tid < 128) lh[tid] = 0;
  __syncthreads();
  for (int i = s + tid; i < e; i += 256)
    atomicAdd(&lh[(pk[i] >> 17) & 127], 1);
  __syncthreads();
  int lane = tid & 63;
  int v = 0, x = 0;
  if (tid < 128){
    v = lh[tid]; x = v;
    #pragma unroll
    for (int o = 1; o < 64; o <<= 1){
      int t = __shfl_up(x, o);
      if (lane >= o) x += t;
    }
    if (tid == 63) sh0 = x;
  }
  __syncthreads();
  if (tid < 128){
    int excl = x - v + (tid >= 64 ? sh0 : 0);
    cur[tid] = s + excl;
    int loc = (lb << 7) + tid;
    if (loc < Ngr) ptr_all[pbase + loc] = s + excl;
  }
  __syncthreads();
  for (int i = s + tid; i < e; i += 256){
    unsigned p = pk[i];
    int dl = (p >> 17) & 127;
    int pos = atomicAdd(&cur[dl], 1);
    col[pos] = (int)(p & 0x1FFFFu);
  }
  if (lb == 0 && tid == 0) ptr_all[pbase + Ngr] = gbase[bend];
}

// ---------------- prep: weight compose + bias + f2b/f2fp8, one dispatch ----------------
#define PREP_F2B_BLOCKS (((NG+ND)*32)/256)   // 8750
__global__ __launch_bounds__(256) void k_prep(
    const float* __restrict__ Wd1, const float* __restrict__ Ws1, const float* __restrict__ Wu1,
    const float* __restrict__ Wd2, const float* __restrict__ Ws2, const float* __restrict__ Wu2,
    const float* __restrict__ bd1, const float* __restrict__ bs1, const float* __restrict__ bu1,
    const float* __restrict__ bd2, const float* __restrict__ bs2, const float* __restrict__ bu2,
    float* __restrict__ AB, float* __restrict__ cv,
    const float* __restrict__ Xg, const float* __restrict__ Xd,
    unsigned short* __restrict__ Yg, unsigned short* __restrict__ Yd,
    unsigned* __restrict__ Yg8, unsigned* __restrict__ Yd8){
  const int b = blockIdx.x, tid = threadIdx.x;
  if (b < 768){
    int idx = b*256 + tid;
    int layer = idx / 98304;
    int r0 = idx - layer*98304;
    int mat = r0 >> 14;
    int r   = (r0 >> 7) & 127;
    int c   = r0 & 127;
    int i   = mat >> 1;
    int isB = mat & 1;
    const float* Wd = layer ? Wd2 : Wd1;
    const float* Ws = layer ? Ws2 : Ws1;
    const float* Wu = layer ? Wu2 : Wu1;
    const float* P = (isB ? Ws : Wd) + i*16384 + r*128;
    const float* Q = Wu + i*32768 + (isB ? 16384 : 0) + c;
    float s = 0.f;
    for (int h = 0; h < 128; ++h) s += P[h] * Q[h*128];
    AB[idx] = s;
  } else if (b < 771){
    int idx = (b - 768)*256 + tid;
    if (idx >= 768) return;
    int layer = idx / 384;
    int r = idx - layer*384;
    int i = r >> 7, h = r & 127;
    const float* bd = layer ? bd2 : bd1;
    const float* bs = layer ? bs2 : bs1;
    const float* bu = layer ? bu2 : bu1;
    const float* Wu = layer ? Wu2 : Wu1;
    float s = bu[i*128 + h];
    const float* Ut = Wu + i*32768 + h;
    const float* Ub = Ut + 16384;
    for (int k = 0; k < 128; ++k)
      s += bd[i*128 + k] * Ut[k*128] + bs[i*128 + k] * Ub[k*128];
    cv[idx] = s;
  } else {
    int idx = (b - 771)*256 + tid;
    const int GQ = NG*32;
    const float* X; unsigned short* Y; unsigned* Y8; int i;
    if (idx < GQ){ X = Xg; Y = Yg; Y8 = Yg8; i = idx; }
    else         { X = Xd; Y = Yd; Y8 = Yd8; i = idx - GQ; }
    float4 v = ((const float4*)X)[i];
    ushort4 o;
    o.x = f2b(v.x); o.y = f2b(v.y); o.z = f2b(v.z); o.w = f2b(v.w);
    ((ushort4*)Y)[i] = o;
    Y8[i] = fp8x4_enc(v.x, v.y, v.z, v.w);
  }
}

// pack B-fragment order (hi-only), both layers + gene/dis in one kernel
__global__ __launch_bounds__(256) void k_pack(const float* __restrict__ AB, const float* __restrict__ cv,
                                              bf16* __restrict__ Wg1, bf16* __restrict__ Wd1p,
                                              bf16* __restrict__ Wg2, bf16* __restrict__ Wd2p,
                                              float* __restrict__ cg1, float* __restrict__ cd1,
                                              float* __restrict__ cg2, float* __restrict__ cd2){
  int idx = blockIdx.x*256 + threadIdx.x;
  int layer = idx / 81920;
  int rem = idx - layer*81920;
  const float* ABl = AB + layer*98304;
  const float* cvl = cv + layer*384;
  if (rem < 49152){
    int n0  = rem / 6144;
    int r2  = rem - n0*6144;
    int ks  = r2 >> 9;
    int lane = (r2 >> 3) & 63;
    int j   = r2 & 7;
    int k   = ks*32 + (lane >> 4)*8 + j;
    int c   = n0*16 + (lane & 15);
    float v;
    if      (k < 128) v = 0.5f*(ABl[0*16384 + k*128 + c] + ABl[4*16384 + k*128 + c]);
    else if (k < 256) v = 0.5f* ABl[1*16384 + (k-128)*128 + c];
    else              v = 0.5f* ABl[5*16384 + (k-256)*128 + c];
    bf16* W = layer ? Wg2 : Wg1;
    ((unsigned short*)W)[rem] = f2b(v);
    if (rem < 128){
      float* cg = layer ? cg2 : cg1;
      cg[rem] = 0.5f*(cvl[rem] + cvl[256 + rem]);
    }
  } else {
    int d = rem - 49152;
    int n0  = d >> 12;
    int ks  = (d >> 9) & 7;
    int lane = (d >> 3) & 63;
    int j   = d & 7;
    int k   = ks*32 + (lane >> 4)*8 + j;
    int c   = n0*16 + (lane & 15);
    float v = (k < 128) ? ABl[2*16384 + k*128 + c] : ABl[3*16384 + (k-128)*128 + c];
    bf16* W = layer ? Wd2p : Wd1p;
    ((unsigned short*)W)[d] = f2b(v);
    if (d < 128){
      float* cd = layer ? cd2 : cd1;
      cd[d] = cvl[128 + d];
    }
  }
}

// ---------------- fused layer: per-block agg (LDS) -> MFMA GEMM -> (BN partials) ----------------
#define GBG32 ((NG+31)/32)
#define GBD32 ((ND+31)/32)

template<int KS, int DO_BN>
__device__ __forceinline__ void layer_body(
    const bf16* __restrict__ X0,
    const unsigned* __restrict__ S8a, const unsigned* __restrict__ S8b,
    const int* __restrict__ ptrA, const int* __restrict__ ptrB,
    const int* __restrict__ col,
    const bf16* __restrict__ Wp, const float* __restrict__ cvec,
    unsigned short* __restrict__ Out, float* __restrict__ bnglob,
    int M, int blk, short (*lds_agg)[32][LSTR], float* bnacc){
  const int tid = threadIdx.x;
  const int row0 = blk*32;

  // ---- agg phase: quarter-wave per (row, graph) task; identical math to old k_agg ----
  {
    const int qw = tid >> 4, lane = tid & 15;
    const int loff = lane*2;
    const int NT = (KS == 12) ? 64 : 32;
    for (int t = qw; t < NT; t += 16){
      int lr  = (KS == 12) ? (t >> 1) : t;
      int row = row0 + lr;
      if (row < M){
        int g = (KS == 12) ? (t & 1) : 0;
        const unsigned* X8 = g ? S8b : S8a;
        const int* ptr = g ? ptrB : ptrA;
        int s = ptr[row], e = ptr[row+1];
        float a[8];
        #pragma unroll
        for (int j = 0; j < 8; ++j) a[j] = 0.f;
        int i = s;
        for (; i + 4 <= e; i += 4){
          uint2 u0 = *(const uint2*)(X8 + (size_t)col[i  ]*32 + loff);
          uint2 u1 = *(const uint2*)(X8 + (size_t)col[i+1]*32 + loff);
          uint2 u2 = *(const uint2*)(X8 + (size_t)col[i+2]*32 + loff);
          uint2 u3 = *(const uint2*)(X8 + (size_t)col[i+3]*32 + loff);
          fp8x4_acc(u0.x, a);     fp8x4_acc(u0.y, a+4);
          fp8x4_acc(u1.x, a);     fp8x4_acc(u1.y, a+4);
          fp8x4_acc(u2.x, a);     fp8x4_acc(u2.y, a+4);
          fp8x4_acc(u3.x, a);     fp8x4_acc(u3.y, a+4);
        }
        for (; i < e; ++i){
          uint2 u = *(const uint2*)(X8 + (size_t)col[i]*32 + loff);
          fp8x4_acc(u.x, a);      fp8x4_acc(u.y, a+4);
        }
        float inv = 1.f / fmaxf((float)(e - s), 1.f);
        bf16x8 o;
        #pragma unroll
        for (int j = 0; j < 8; ++j) o[j] = (short)f2b(a[j]*inv);
        *(bf16x8*)&lds_agg[g][lr][lane*8] = o;
      }
    }
  }
  __syncthreads();

  // ---- GEMM phase: identical math; X1/X2 from padded LDS ----
  const int wave = tid >> 6, lane = tid & 63;
  const int lrow = lane & 15, quad = lane >> 4;
  f32x4 acc[2][2];
  #pragma unroll
  for (int p = 0; p < 2; ++p)
    #pragma unroll
    for (int t = 0; t < 2; ++t) acc[p][t] = 0.0f;
  const bf16x8* wp = (const bf16x8*)Wp;
  const int f00 = (2*wave*KS)*64 + lane;
  #pragma unroll
  for (int ks = 0; ks < KS; ++ks){
    const int kk = (ks & 3)*32 + quad*8;
    bf16x8 a[2];
    #pragma unroll
    for (int t = 0; t < 2; ++t){
      int ar = row0 + t*16 + lrow; if (ar > M-1) ar = M-1;
      if (ks < 4) a[t] = *(const bf16x8*)(X0 + (size_t)ar*DH + kk);
      else        a[t] = *(const bf16x8*)&lds_agg[(ks >> 2) - 1][ar - row0][kk];
    }
    bf16x8 b0 = wp[f00 + ks*64];
    bf16x8 b1 = wp[f00 + (KS + ks)*64];
    #pragma unroll
    for (int t = 0; t < 2; ++t){
      acc[0][t] = __builtin_amdgcn_mfma_f32_16x16x32_bf16(a[t], b0, acc[0][t], 0, 0, 0);
      acc[1][t] = __builtin_amdgcn_mfma_f32_16x16x32_bf16(a[t], b1, acc[1][t], 0, 0, 0);
    }
  }

  // ---- epilogue: store + optional BN partial sums ----
  #pragma unroll
  for (int p = 0; p < 2; ++p){
    int c = (2*wave + p)*16 + lrow;
    float cb = cvec[c];
    float sl = 0.f, ql = 0.f;
    #pragma unroll
    for (int t = 0; t < 2; ++t){
      #pragma unroll
      for (int r = 0; r < 4; ++r){
        int row = row0 + t*16 + quad*4 + r;
        if (row < M){
          unsigned short us = f2b(acc[p][t][r] + cb);
          Out[(size_t)row*DH + c] = us;
          if (DO_BN){
            float f = bf2f((short)us);
            sl += f; ql += f*f;
          }
        }
      }
    }
    if (DO_BN){
      atomicAdd(&bnacc[c], sl);
      atomicAdd(&bnacc[128 + c], ql);
    }
  }
  if (DO_BN){
    __syncthreads();
    atomicAdd(&bnglob[tid], bnacc[tid]);
  }
}

template<int DO_BN>
__global__ __launch_bounds__(256) void k_layer(
    const bf16* __restrict__ Xg, const bf16* __restrict__ Xd,
    const unsigned* __restrict__ xg8, const unsigned* __restrict__ xd8,
    const int* __restrict__ ptr_all, const int* __restrict__ col,
    const bf16* __restrict__ Wg, const float* __restrict__ cg, unsigned short* __restrict__ Og,
    const bf16* __restrict__ Wd, const float* __restrict__ cd, unsigned short* __restrict__ Od,
    float* __restrict__ bnsum){
  __shared__ short lds_agg[2][32][LSTR];
  __shared__ float bnacc[256];
  if (DO_BN) bnacc[threadIdx.x] = 0.f;     // agg-phase __syncthreads covers visibility
  if ((int)blockIdx.x < GBG32)
    layer_body<12, DO_BN>(Xg, xg8, xd8, ptr_all + PB0, ptr_all + PB2, col,
                          Wg, cg, Og, bnsum, NG, blockIdx.x, lds_agg, bnacc);
  else
    layer_body<8, DO_BN>(Xd, xg8, xg8, ptr_all + PB1, ptr_all + PB1, col,
                         Wd, cd, Od, bnsum + 256, ND, blockIdx.x - GBG32, lds_agg, bnacc);
}

// BN + LeakyReLU, both matrices; writes bf16 + fp8 copies
__global__ __launch_bounds__(256) void k_bn_apply(const bf16* __restrict__ Xgb, const bf16* __restrict__ Xdb,
    const float* __restrict__ sums, const float* __restrict__ gamma, const float* __restrict__ beta,
    unsigned short* __restrict__ Yg, unsigned short* __restrict__ Yd,
    uint2* __restrict__ Yg8, uint2* __restrict__ Yd8){
  __shared__ float sc[256], sb[256];
  int tid = threadIdx.x;
  {
    int g = tid >> 7, c = tid & 127;
    float invN = g ? (1.f/ND) : (1.f/NG);
    const float* sm = sums + g*256;
    float m = sm[c]*invN;
    float v = sm[128 + c]*invN - m*m;
    float s = rsqrtf(v + 1e-5f) * gamma[g*128 + c];
    sc[tid] = s;
    sb[tid] = beta[g*128 + c] - m*s;
  }
  __syncthreads();
  const int GT = NG*16;
  const int TOT = GT + ND*16;
  for (int idx = blockIdx.x*256 + tid; idx < TOT; idx += gridDim.x*256){
    const bf16x8* src; bf16x8* dst; uint2* dst8; int i, cb;
    if (idx < GT){ src = (const bf16x8*)Xgb; dst = (bf16x8*)Yg; dst8 = Yg8; i = idx; cb = 0; }
    else         { src = (const bf16x8*)Xdb; dst = (bf16x8*)Yd; dst8 = Yd8; i = idx - GT; cb = 128; }
    bf16x8 v = src[i];
    int c = cb + (i & 15)*8;
    float y[8];
    bf16x8 o;
    #pragma unroll
    for (int j = 0; j < 8; ++j){
      float t = bf2f(v[j])*sc[c+j] + sb[c+j];
      t = t >= 0.f ? t : 0.01f*t;
      y[j] = t;
      o[j] = (short)f2b(t);
    }
    dst[i] = o;
    uint2 p;
    p.x = fp8x4_enc(y[0], y[1], y[2], y[3]);
    p.y = fp8x4_enc(y[4], y[5], y[6], y[7]);
    dst8[i] = p;
  }
}

// ---------------- decoder: 2 edges per quarter-wave (bf16 in) ----------------
__global__ __launch_bounds__(256) void k_decode(const bf16* __restrict__ G, const bf16* __restrict__ Dd,
    const int* __restrict__ ls, const int* __restrict__ ld, float* __restrict__ out, int E){
  int p = (blockIdx.x*256 + threadIdx.x) >> 4;
  int lane = threadIdx.x & 15;
  int e0 = p*2, e1 = p*2 + 1;
  if (e0 >= E) return;
  int a0 = ls[e0], b0 = ld[e0];
  int a1 = ls[e1], b1 = ld[e1];
  const size_t loff = (size_t)lane*8;
  bf16x8 g0 = *(const bf16x8*)(G  + (size_t)a0*DH + loff);
  bf16x8 d0 = *(const bf16x8*)(Dd + (size_t)b0*DH + loff);
  bf16x8 g1 = *(const bf16x8*)(G  + (size_t)a1*DH + loff);
  bf16x8 d1 = *(const bf16x8*)(Dd + (size_t)b1*DH + loff);
  float s0 = 0.f, s1 = 0.f;
  #pragma unroll
  for (int j = 0; j < 8; ++j){
    s0 += bf2f(g0[j])*bf2f(d0[j]);
    s1 += bf2f(g1[j])*bf2f(d1[j]);
  }
  #pragma unroll
  for (int off = 8; off; off >>= 1){
    s0 += __shfl_down(s0, off, 16);
    s1 += __shfl_down(s1, off, 16);
  }
  if (lane == 0){ out[e0] = s0; out[e1] = s1; }
}

// ---------------- launch ----------------
extern "C" void kernel_launch(void* const* d_in, const int* in_sizes, int n_in,
                              void* d_out, int out_size, void* d_ws, size_t ws_size,
                              hipStream_t stream){
  const float* x_gene = (const float*)d_in[0];
  const float* x_dis  = (const float*)d_in[1];
  const float* Wd1 = (const float*)d_in[2];
  const float* Ws1 = (const float*)d_in[3];
  const float* Wu1 = (const float*)d_in[4];
  const float* bd1 = (const float*)d_in[5];
  const float* bs1 = (const float*)d_in[6];
  const float* bu1 = (const float*)d_in[7];
  const float* Wd2 = (const float*)d_in[8];
  const float* Ws2 = (const float*)d_in[9];
  const float* Wu2 = (const float*)d_in[10];
  const float* bd2 = (const float*)d_in[11];
  const float* bs2 = (const float*)d_in[12];
  const float* bu2 = (const float*)d_in[13];
  const float* bng = (const float*)d_in[14];
  const float* bnb = (const float*)d_in[15];
  const int* gg_src  = (const int*)d_in[16];
  const int* gg_dst  = (const int*)d_in[17];
  const int* gda_src = (const int*)d_in[18];
  const int* gda_dst = (const int*)d_in[19];
  const int* lsrc = (const int*)d_in[20];
  const int* ldst = (const int*)d_in[21];

  char* ws = (char*)d_ws;
  size_t off = 0;
  auto alloc = [&](size_t bytes)->void*{
    void* p = ws + off; off += (bytes + 255) & ~(size_t)255; return p;
  };
  int* hist    = (int*)alloc(960*4);
  float* bnsum = (float*)alloc(2*256*4);
  int* gbase   = (int*)alloc(960*4);
  int* gcur    = (int*)alloc(960*4);
  int* ptr_all = (int*)alloc((size_t)(NG+1+ND+1+NG+1)*4);
  int* col     = (int*)alloc((size_t)(EGG+2*EGDA)*4);
  unsigned* pk = (unsigned*)alloc((size_t)(EGG+2*EGDA)*4);
  float* AB  = (float*)alloc(2*98304*4);
  float* cv  = (float*)alloc(2*384*4);
  float* cg1 = (float*)alloc(128*4);
  float* cd1 = (float*)alloc(128*4);
  float* cg2 = (float*)alloc(128*4);
  float* cd2 = (float*)alloc(128*4);
  bf16* Wg1  = (bf16*)alloc(49152*2);
  bf16* Wp1  = (bf16*)alloc(32768*2);
  bf16* Wg2  = (bf16*)alloc(49152*2);
  bf16* Wp2  = (bf16*)alloc(32768*2);
  bf16* xgb  = (bf16*)alloc((size_t)NG*DH*2);
  bf16* xdb  = (bf16*)alloc((size_t)ND*DH*2);
  unsigned* xg8  = (unsigned*)alloc((size_t)NG*DH);
  unsigned* xd8  = (unsigned*)alloc((size_t)ND*DH);
  unsigned* Xg28 = (unsigned*)alloc((size_t)NG*DH);
  unsigned* Xd28 = (unsigned*)alloc((size_t)ND*DH);
  bf16* Xg2b = (bf16*)alloc((size_t)NG*DH*2);
  bf16* Xd2b = (bf16*)alloc((size_t)ND*DH*2);
  bf16* outgb = (bf16*)alloc((size_t)NG*DH*2);
  bf16* outdb = (bf16*)alloc((size_t)ND*DH*2);

  hipMemsetAsync(hist, 0, 960*4 + 512*4, stream);

  // --- CSR build: all 3 graphs ---
  {
    dim3 gh(96, 3);
    k_hist1<<<gh,256,0,stream>>>(gg_dst, gda_dst, gda_src, hist);
    k_exscan<<<1,1024,0,stream>>>(hist, gbase, gcur, TBP);
    dim3 gs(196, 3);
    k_scatter1<<<gs,256,0,stream>>>(gg_dst, gg_src, gda_dst, gda_src, gcur, pk);
    k_csr2<<<TB,256,0,stream>>>(pk, gbase, ptr_all, col);
  }

  // --- prep: weight compose + bias + f2b/f2fp8 (one dispatch) ---
  k_prep<<<771 + PREP_F2B_BLOCKS,256,0,stream>>>(
      Wd1, Ws1, Wu1, Wd2, Ws2, Wu2, bd1, bs1, bu1, bd2, bs2, bu2,
      AB, cv, x_gene, x_dis, (unsigned short*)xgb, (unsigned short*)xdb, xg8, xd8);
  k_pack<<<640,256,0,stream>>>(AB, cv, Wg1, Wp1, Wg2, Wp2, cg1, cd1, cg2, cd2);

  // --- layer 1 (fused agg+gemm+bn-partials) ---
  k_layer<1><<<GBG32+GBD32,256,0,stream>>>(xgb, xdb, xg8, xd8, ptr_all, col,
                                           Wg1, cg1, (unsigned short*)outgb,
                                           Wp1, cd1, (unsigned short*)outdb, bnsum);
  k_bn_apply<<<1024,256,0,stream>>>(outgb, outdb, bnsum, bng, bnb,
                                    (unsigned short*)Xg2b, (unsigned short*)Xd2b,
                                    (uint2*)Xg28, (uint2*)Xd28);

  // --- layer 2 (fused agg+gemm) ---
  k_layer<0><<<GBG32+GBD32,256,0,stream>>>(Xg2b, Xd2b, Xg28, Xd28, ptr_all, col,
                                           Wg2, cg2, (unsigned short*)outgb,
                                           Wp2, cd2, (unsigned short*)outdb, bnsum);

  // --- decoder ---
  k_decode<<<ELAB*16/2/256,256,0,stream>>>(outgb, outdb, lsrc, ldst, (float*)d_out, ELAB);
}

// Round 14
// 329.893 us; speedup vs baseline: 1.0782x; 1.0692x over previous
//
#include <hip/hip_runtime.h>
#include <hip/hip_bf16.h>
#include <cstddef>

#define NG   50000
#define ND   20000
#define DH   128
#define EGG  800000
#define EGDA 400000
#define ELAB 200000

#define B1G 391
#define B1D 157
#define TB  939
#define CAP 4096          // slots per bucket (max observed fill ~2550)
// se_all row-index bases
#define SE0 0
#define SE1 NG
#define SE2 (NG+ND)

typedef __hip_bfloat16  bf16;
typedef __attribute__((ext_vector_type(8))) short bf16x8;
typedef __attribute__((ext_vector_type(4))) float f32x4;
typedef __attribute__((ext_vector_type(2))) float f32x2;

__device__ __forceinline__ float bf2f(short s){
  return __uint_as_float(((unsigned)(unsigned short)s) << 16);
}
__device__ __forceinline__ unsigned short f2b(float x){
  unsigned u = __float_as_uint(x);
  return (unsigned short)((u + 0x7FFF + ((u >> 16) & 1)) >> 16);
}

// ---- fp8 e4m3 (OCP) helpers ----
__device__ __forceinline__ float fp8_dec1(unsigned v){
  unsigned s = (v >> 7) & 1, e = (v >> 3) & 15, m = v & 7;
  float r = e ? __uint_as_float(((e + 120) << 23) | (m << 20))
              : (float)m * 0.001953125f;
  return s ? -r : r;
}
__device__ __forceinline__ unsigned fp8_enc1(float x){
  float a = fabsf(x);
  if (a > 448.f) a = 448.f;
  unsigned sgn = (__float_as_uint(x) >> 31) << 7;
  unsigned res;
  if (a < 0.015625f){
    res = (unsigned)__float2int_rn(a * 512.f);
    if (res > 7) res = 8;
    if (res == 8) res = 0x08;
  } else {
    unsigned ab = __float_as_uint(a);
    unsigned r = ab + 0x0007FFFF + ((ab >> 20) & 1);
    int e = (int)(r >> 23) - 127;
    unsigned m = (r >> 20) & 7;
    if (e > 8){ e = 8; m = 6; }
    res = ((unsigned)(e + 7) << 3) | m;
  }
  return res | sgn;
}

__device__ __forceinline__ void fp8x4_acc(unsigned w, float* a){
#if __has_builtin(__builtin_amdgcn_cvt_pk_f32_fp8)
  f32x2 p0 = __builtin_amdgcn_cvt_pk_f32_fp8((int)w, false);
  f32x2 p1 = __builtin_amdgcn_cvt_pk_f32_fp8((int)w, true);
  a[0] += p0.x; a[1] += p0.y; a[2] += p1.x; a[3] += p1.y;
#else
  a[0] += fp8_dec1(w & 255);
  a[1] += fp8_dec1((w >> 8) & 255);
  a[2] += fp8_dec1((w >> 16) & 255);
  a[3] += fp8_dec1(w >> 24);
#endif
}
__device__ __forceinline__ unsigned fp8x4_enc(float x0, float x1, float x2, float x3){
#if __has_builtin(__builtin_amdgcn_cvt_pk_fp8_f32)
  int v = 0;
  v = __builtin_amdgcn_cvt_pk_fp8_f32(x0, x1, v, false);
  v = __builtin_amdgcn_cvt_pk_fp8_f32(x2, x3, v, true);
  return (unsigned)v;
#else
  return fp8_enc1(x0) | (fp8_enc1(x1) << 8) | (fp8_enc1(x2) << 16) | (fp8_enc1(x3) << 24);
#endif
}

// ---------------- CSR build: capacity-padded buckets (no hist/exscan pass) ----------------
// bucket b (global id) owns pk[b*CAP .. b*CAP+CAP); gcur[b] = fill count (zero-init).
__global__ __launch_bounds__(256) void k_scatter1(const int* __restrict__ k0, const int* __restrict__ v0,
                                                  const int* __restrict__ k1, const int* __restrict__ v1,
                                                  int* __restrict__ gcur, unsigned* __restrict__ pk){
  __shared__ int lh[400];
  __shared__ int base[400];
  const int g = blockIdx.y;
  const int n  = (g == 0) ? EGG : EGDA;
  const int B1 = (g == 1) ? B1D : B1G;
  const int bb = (g == 0) ? 0 : (g == 1 ? B1G : B1G + B1D);
  const int* key = (g == 0) ? k0 : (g == 1 ? k1 : v1);
  const int* val = (g == 0) ? v0 : (g == 1 ? v1 : k1);
  const int tid = threadIdx.x;
  const int chunk0 = blockIdx.x*4096;
  if (chunk0 >= n) return;
  for (int t = tid; t < B1; t += 256) lh[t] = 0;
  __syncthreads();
  int kd[16], vv[16];
  #pragma unroll
  for (int it = 0; it < 16; ++it){
    int i = chunk0 + it*256 + tid;
    int k = -1, v = 0;
    if (i < n){ k = key[i]; v = val[i]; atomicAdd(&lh[k >> 7], 1); }
    kd[it] = k; vv[it] = v;
  }
  __syncthreads();
  for (int t = tid; t < B1; t += 256){
    int c = lh[t];
    base[t] = c ? ((bb + t)*CAP + atomicAdd(&gcur[bb + t], c)) : 0;
    lh[t] = 0;
  }
  __syncthreads();
  #pragma unroll
  for (int it = 0; it < 16; ++it){
    int k = kd[it];
    if (k >= 0){
      int b = k >> 7;
      int p = base[b] + atomicAdd(&lh[b], 1);
      pk[p] = ((unsigned)(k & 127) << 17) | (unsigned)vv[it];
    }
  }
}

// per-bucket fine CSR: write se (start,deg) + col
__global__ __launch_bounds__(256) void k_csr2(const unsigned* __restrict__ pk,
                                              const int* __restrict__ gcur,
                                              int2* __restrict__ se_all, int* __restrict__ col){
  __shared__ int lh[128];
  __shared__ int cur[128];
  __shared__ int sh0;
  const int b = blockIdx.x, tid = threadIdx.x;
  int lb, sbase, Ngr;
  if (b < B1G)            { lb = b;             sbase = SE0; Ngr = NG; }
  else if (b < B1G + B1D) { lb = b - B1G;       sbase = SE1; Ngr = ND; }
  else                    { lb = b - B1G - B1D; sbase = SE2; Ngr = NG; }
  const int s = b*CAP, e = s + gcur[b];
  if (tid < 128) lh[tid] = 0;
  __syncthreads();
  for (int i = s + tid; i < e; i += 256)
    atomicAdd(&lh[(pk[i] >> 17) & 127], 1);
  __syncthreads();
  int lane = tid & 63;
  int v = 0, x = 0;
  if (tid < 128){
    v = lh[tid]; x = v;
    #pragma unroll
    for (int o = 1; o < 64; o <<= 1){
      int t = __shfl_up(x, o);
      if (lane >= o) x += t;
    }
    if (tid == 63) sh0 = x;
  }
  __syncthreads();
  if (tid < 128){
    int excl = x - v + (tid >= 64 ? sh0 : 0);
    cur[tid] = s + excl;
    int loc = (lb << 7) + tid;
    if (loc < Ngr) se_all[sbase + loc] = make_int2(s + excl, v);
  }
  __syncthreads();
  for (int i = s + tid; i < e; i += 256){
    unsigned p = pk[i];
    int dl = (p >> 17) & 127;
    int pos = atomicAdd(&cur[dl], 1);
    col[pos] = (int)(p & 0x1FFFFu);
  }
}

// ---------------- prep: weight compose + bias + f2b/f2fp8, one dispatch ----------------
#define PREP_F2B_BLOCKS (((NG+ND)*32)/256)   // 8750
__global__ __launch_bounds__(256) void k_prep(
    const float* __restrict__ Wd1, const float* __restrict__ Ws1, const float* __restrict__ Wu1,
    const float* __restrict__ Wd2, const float* __restrict__ Ws2, const float* __restrict__ Wu2,
    const float* __restrict__ bd1, const float* __restrict__ bs1, const float* __restrict__ bu1,
    const float* __restrict__ bd2, const float* __restrict__ bs2, const float* __restrict__ bu2,
    float* __restrict__ AB, float* __restrict__ cv,
    const float* __restrict__ Xg, const float* __restrict__ Xd,
    unsigned short* __restrict__ Yg, unsigned short* __restrict__ Yd,
    unsigned* __restrict__ Yg8, unsigned* __restrict__ Yd8){
  const int b = blockIdx.x, tid = threadIdx.x;
  if (b < 768){
    int idx = b*256 + tid;
    int layer = idx / 98304;
    int r0 = idx - layer*98304;
    int mat = r0 >> 14;
    int r   = (r0 >> 7) & 127;
    int c   = r0 & 127;
    int i   = mat >> 1;
    int isB = mat & 1;
    const float* Wd = layer ? Wd2 : Wd1;
    const float* Ws = layer ? Ws2 : Ws1;
    const float* Wu = layer ? Wu2 : Wu1;
    const float* P = (isB ? Ws : Wd) + i*16384 + r*128;
    const float* Q = Wu + i*32768 + (isB ? 16384 : 0) + c;
    float s = 0.f;
    for (int h = 0; h < 128; ++h) s += P[h] * Q[h*128];
    AB[idx] = s;
  } else if (b < 771){
    int idx = (b - 768)*256 + tid;
    if (idx >= 768) return;
    int layer = idx / 384;
    int r = idx - layer*384;
    int i = r >> 7, h = r & 127;
    const float* bd = layer ? bd2 : bd1;
    const float* bs = layer ? bs2 : bs1;
    const float* bu = layer ? bu2 : bu1;
    const float* Wu = layer ? Wu2 : Wu1;
    float s = bu[i*128 + h];
    const float* Ut = Wu + i*32768 + h;
    const float* Ub = Ut + 16384;
    for (int k = 0; k < 128; ++k)
      s += bd[i*128 + k] * Ut[k*128] + bs[i*128 + k] * Ub[k*128];
    cv[idx] = s;
  } else {
    int idx = (b - 771)*256 + tid;
    const int GQ = NG*32;
    const float* X; unsigned short* Y; unsigned* Y8; int i;
    if (idx < GQ){ X = Xg; Y = Yg; Y8 = Yg8; i = idx; }
    else         { X = Xd; Y = Yd; Y8 = Yd8; i = idx - GQ; }
    float4 v = ((const float4*)X)[i];
    ushort4 o;
    o.x = f2b(v.x); o.y = f2b(v.y); o.z = f2b(v.z); o.w = f2b(v.w);
    ((ushort4*)Y)[i] = o;
    Y8[i] = fp8x4_enc(v.x, v.y, v.z, v.w);
  }
}

// pack B-fragment order (hi-only), both layers + gene/dis in one kernel
__global__ __launch_bounds__(256) void k_pack(const float* __restrict__ AB, const float* __restrict__ cv,
                                              bf16* __restrict__ Wg1, bf16* __restrict__ Wd1p,
                                              bf16* __restrict__ Wg2, bf16* __restrict__ Wd2p,
                                              float* __restrict__ cg1, float* __restrict__ cd1,
                                              float* __restrict__ cg2, float* __restrict__ cd2){
  int idx = blockIdx.x*256 + threadIdx.x;
  int layer = idx / 81920;
  int rem = idx - layer*81920;
  const float* ABl = AB + layer*98304;
  const float* cvl = cv + layer*384;
  if (rem < 49152){
    int n0  = rem / 6144;
    int r2  = rem - n0*6144;
    int ks  = r2 >> 9;
    int lane = (r2 >> 3) & 63;
    int j   = r2 & 7;
    int k   = ks*32 + (lane >> 4)*8 + j;
    int c   = n0*16 + (lane & 15);
    float v;
    if      (k < 128) v = 0.5f*(ABl[0*16384 + k*128 + c] + ABl[4*16384 + k*128 + c]);
    else if (k < 256) v = 0.5f* ABl[1*16384 + (k-128)*128 + c];
    else              v = 0.5f* ABl[5*16384 + (k-256)*128 + c];
    bf16* W = layer ? Wg2 : Wg1;
    ((unsigned short*)W)[rem] = f2b(v);
    if (rem < 128){
      float* cg = layer ? cg2 : cg1;
      cg[rem] = 0.5f*(cvl[rem] + cvl[256 + rem]);
    }
  } else {
    int d = rem - 49152;
    int n0  = d >> 12;
    int ks  = (d >> 9) & 7;
    int lane = (d >> 3) & 63;
    int j   = d & 7;
    int k   = ks*32 + (lane >> 4)*8 + j;
    int c   = n0*16 + (lane & 15);
    float v = (k < 128) ? ABl[2*16384 + k*128 + c] : ABl[3*16384 + (k-128)*128 + c];
    bf16* W = layer ? Wd2p : Wd1p;
    ((unsigned short*)W)[d] = f2b(v);
    if (d < 128){
      float* cd = layer ? cd2 : cd1;
      cd[d] = cvl[128 + d];
    }
  }
}

// ---------------- mean aggregation: quarter-wave per dst, fp8 rows (8 B/lane), 4x unroll ----------------
__global__ __launch_bounds__(256) void k_agg(const unsigned* __restrict__ Xg8, const unsigned* __restrict__ Xd8,
    const int2* __restrict__ se_all, const int* __restrict__ col,
    bf16* __restrict__ OutGG, bf16* __restrict__ OutGDA, bf16* __restrict__ OutREV){
  int q = (blockIdx.x*256 + threadIdx.x) >> 4;
  int lane = threadIdx.x & 15;
  const unsigned* X; bf16* Out; const int2* se; int dst;
  if (q < NG)          { X = Xg8; Out = OutGG;  se = se_all + SE0; dst = q; }
  else if (q < NG+ND)  { X = Xg8; Out = OutGDA; se = se_all + SE1; dst = q - NG; }
  else                 { X = Xd8; Out = OutREV; se = se_all + SE2; dst = q - NG - ND; }
  int2 sd = se[dst];
  int s = sd.x, e = sd.x + sd.y;
  float a[8];
  #pragma unroll
  for (int j = 0; j < 8; ++j) a[j] = 0.f;
  const int loff = lane*2;
  int i = s;
  for (; i + 4 <= e; i += 4){
    uint2 u0 = *(const uint2*)(X + (size_t)col[i  ]*32 + loff);
    uint2 u1 = *(const uint2*)(X + (size_t)col[i+1]*32 + loff);
    uint2 u2 = *(const uint2*)(X + (size_t)col[i+2]*32 + loff);
    uint2 u3 = *(const uint2*)(X + (size_t)col[i+3]*32 + loff);
    fp8x4_acc(u0.x, a);     fp8x4_acc(u0.y, a+4);
    fp8x4_acc(u1.x, a);     fp8x4_acc(u1.y, a+4);
    fp8x4_acc(u2.x, a);     fp8x4_acc(u2.y, a+4);
    fp8x4_acc(u3.x, a);     fp8x4_acc(u3.y, a+4);
  }
  for (; i < e; ++i){
    uint2 u = *(const uint2*)(X + (size_t)col[i]*32 + loff);
    fp8x4_acc(u.x, a);      fp8x4_acc(u.y, a+4);
  }
  float inv = 1.f / fmaxf((float)(e - s), 1.f);
  bf16x8 o;
  #pragma unroll
  for (int j = 0; j < 8; ++j) o[j] = (short)f2b(a[j]*inv);
  *(bf16x8*)(Out + (size_t)dst*DH + (size_t)lane*8) = o;
}

// ---------------- concat-K MFMA GEMM: 32 rows/block for occupancy, no LDS, hi-only ----------------
template<int KS>
__device__ __forceinline__ void gemm_body(
    const bf16* __restrict__ X0, const bf16* __restrict__ X1, const bf16* __restrict__ X2,
    const bf16* __restrict__ Wp, const float* __restrict__ cvec,
    unsigned short* __restrict__ Out, int M, int blk){
  const int tid = threadIdx.x;
  const int wave = tid >> 6, lane = tid & 63;
  const int lrow = lane & 15, quad = lane >> 4;
  const int row0 = blk*32;
  const bf16* Xs[3] = {X0, X1, X2};
  f32x4 acc[2][2];
  #pragma unroll
  for (int p = 0; p < 2; ++p)
    #pragma unroll
    for (int t = 0; t < 2; ++t) acc[p][t] = 0.0f;
  const bf16x8* wp = (const bf16x8*)Wp;
  const int f00 = (2*wave*KS)*64 + lane;
  #pragma unroll
  for (int ks = 0; ks < KS; ++ks){
    const bf16* Xm = Xs[ks >> 2];
    const int kk = (ks & 3)*32 + quad*8;
    bf16x8 a[2];
    #pragma unroll
    for (int t = 0; t < 2; ++t){
      int ar = row0 + t*16 + lrow; if (ar > M-1) ar = M-1;
      a[t] = *(const bf16x8*)(Xm + (size_t)ar*DH + kk);
    }
    bf16x8 b0 = wp[f00 + ks*64];
    bf16x8 b1 = wp[f00 + (KS + ks)*64];
    #pragma unroll
    for (int t = 0; t < 2; ++t){
      acc[0][t] = __builtin_amdgcn_mfma_f32_16x16x32_bf16(a[t], b0, acc[0][t], 0, 0, 0);
      acc[1][t] = __builtin_amdgcn_mfma_f32_16x16x32_bf16(a[t], b1, acc[1][t], 0, 0, 0);
    }
  }
  #pragma unroll
  for (int p = 0; p < 2; ++p){
    int c = (2*wave + p)*16 + lrow;
    float cb = cvec[c];
    #pragma unroll
    for (int t = 0; t < 2; ++t){
      #pragma unroll
      for (int r = 0; r < 4; ++r){
        int row = row0 + t*16 + quad*4 + r;
        if (row < M) Out[(size_t)row*DH + c] = f2b(acc[p][t][r] + cb);
      }
    }
  }
}

#define GBGENE ((NG+31)/32)
#define GBDIS  ((ND+31)/32)

__global__ __launch_bounds__(256) void k_gemm(
    const bf16* __restrict__ Xg, const bf16* __restrict__ Ag, const bf16* __restrict__ Rg,
    const bf16* __restrict__ Wg, const float* __restrict__ cg, unsigned short* __restrict__ Og,
    const bf16* __restrict__ Xd, const bf16* __restrict__ Ad,
    const bf16* __restrict__ Wd, const float* __restrict__ cd, unsigned short* __restrict__ Od){
  if ((int)blockIdx.x < GBGENE)
    gemm_body<12>(Xg, Ag, Rg, Wg, cg, Og, NG, blockIdx.x);
  else
    gemm_body<8>(Xd, Ad, Ad, Wd, cd, Od, ND, blockIdx.x - GBGENE);
}

// ---------------- BatchNorm stats (both matrices, one kernel) ----------------
#define SBG 192
#define SBD 64
__global__ __launch_bounds__(256) void k_bn_stats(const bf16* __restrict__ Xgb, const bf16* __restrict__ Xdb,
                                                  float* __restrict__ sums){
  __shared__ float acc[256];
  int tid = threadIdx.x;
  acc[tid] = 0.f;
  __syncthreads();
  int g = (int)blockIdx.x >= SBG;
  int bidx = blockIdx.x - (g ? SBG : 0);
  int NB = g ? SBD : SBG;
  int N  = g ? ND : NG;
  const bf16* Xb = g ? Xdb : Xgb;
  float* sm = sums + g*256;
  int c8 = (tid & 15)*8;
  int rl = tid >> 4;
  float s[8], q[8];
  #pragma unroll
  for (int j = 0; j < 8; ++j){ s[j] = 0.f; q[j] = 0.f; }
  for (int r = bidx*16 + rl; r < N; r += NB*16){
    bf16x8 v = *(const bf16x8*)(Xb + (size_t)r*DH + c8);
    #pragma unroll
    for (int j = 0; j < 8; ++j){
      float f = bf2f(v[j]);
      s[j] += f; q[j] += f*f;
    }
  }
  #pragma unroll
  for (int j = 0; j < 8; ++j){
    atomicAdd(&acc[c8+j], s[j]);
    atomicAdd(&acc[128+c8+j], q[j]);
  }
  __syncthreads();
  atomicAdd(&sm[tid], acc[tid]);
}

// BN + LeakyReLU, both matrices; writes bf16 + fp8 copies
__global__ __launch_bounds__(256) void k_bn_apply(const bf16* __restrict__ Xgb, const bf16* __restrict__ Xdb,
    const float* __restrict__ sums, const float* __restrict__ gamma, const float* __restrict__ beta,
    unsigned short* __restrict__ Yg, unsigned short* __restrict__ Yd,
    uint2* __restrict__ Yg8, uint2* __restrict__ Yd8){
  __shared__ float sc[256], sb[256];
  int tid = threadIdx.x;
  {
    int g = tid >> 7, c = tid & 127;
    float invN = g ? (1.f/ND) : (1.f/NG);
    const float* sm = sums + g*256;
    float m = sm[c]*invN;
    float v = sm[128 + c]*invN - m*m;
    float s = rsqrtf(v + 1e-5f) * gamma[g*128 + c];
    sc[tid] = s;
    sb[tid] = beta[g*128 + c] - m*s;
  }
  __syncthreads();
  const int GT = NG*16;
  const int TOT = GT + ND*16;
  for (int idx = blockIdx.x*256 + tid; idx < TOT; idx += gridDim.x*256){
    const bf16x8* src; bf16x8* dst; uint2* dst8; int i, cb;
    if (idx < GT){ src = (const bf16x8*)Xgb; dst = (bf16x8*)Yg; dst8 = Yg8; i = idx; cb = 0; }
    else         { src = (const bf16x8*)Xdb; dst = (bf16x8*)Yd; dst8 = Yd8; i = idx - GT; cb = 128; }
    bf16x8 v = src[i];
    int c = cb + (i & 15)*8;
    float y[8];
    bf16x8 o;
    #pragma unroll
    for (int j = 0; j < 8; ++j){
      float t = bf2f(v[j])*sc[c+j] + sb[c+j];
      t = t >= 0.f ? t : 0.01f*t;
      y[j] = t;
      o[j] = (short)f2b(t);
    }
    dst[i] = o;
    uint2 p;
    p.x = fp8x4_enc(y[0], y[1], y[2], y[3]);
    p.y = fp8x4_enc(y[4], y[5], y[6], y[7]);
    dst8[i] = p;
  }
}

// ---------------- decoder: 2 edges per quarter-wave (bf16 in) ----------------
__global__ __launch_bounds__(256) void k_decode(const bf16* __restrict__ G, const bf16* __restrict__ Dd,
    const int* __restrict__ ls, const int* __restrict__ ld, float* __restrict__ out, int E){
  int p = (blockIdx.x*256 + threadIdx.x) >> 4;
  int lane = threadIdx.x & 15;
  int e0 = p*2, e1 = p*2 + 1;
  if (e0 >= E) return;
  int a0 = ls[e0], b0 = ld[e0];
  int a1 = ls[e1], b1 = ld[e1];
  const size_t loff = (size_t)lane*8;
  bf16x8 g0 = *(const bf16x8*)(G  + (size_t)a0*DH + loff);
  bf16x8 d0 = *(const bf16x8*)(Dd + (size_t)b0*DH + loff);
  bf16x8 g1 = *(const bf16x8*)(G  + (size_t)a1*DH + loff);
  bf16x8 d1 = *(const bf16x8*)(Dd + (size_t)b1*DH + loff);
  float s0 = 0.f, s1 = 0.f;
  #pragma unroll
  for (int j = 0; j < 8; ++j){
    s0 += bf2f(g0[j])*bf2f(d0[j]);
    s1 += bf2f(g1[j])*bf2f(d1[j]);
  }
  #pragma unroll
  for (int off = 8; off; off >>= 1){
    s0 += __shfl_down(s0, off, 16);
    s1 += __shfl_down(s1, off, 16);
  }
  if (lane == 0){ out[e0] = s0; out[e1] = s1; }
}

// ---------------- launch ----------------
extern "C" void kernel_launch(void* const* d_in, const int* in_sizes, int n_in,
                              void* d_out, int out_size, void* d_ws, size_t ws_size,
                              hipStream_t stream){
  const float* x_gene = (const float*)d_in[0];
  const float* x_dis  = (const float*)d_in[1];
  const float* Wd1 = (const float*)d_in[2];
  const float* Ws1 = (const float*)d_in[3];
  const float* Wu1 = (const float*)d_in[4];
  const float* bd1 = (const float*)d_in[5];
  const float* bs1 = (const float*)d_in[6];
  const float* bu1 = (const float*)d_in[7];
  const float* Wd2 = (const float*)d_in[8];
  const float* Ws2 = (const float*)d_in[9];
  const float* Wu2 = (const float*)d_in[10];
  const float* bd2 = (const float*)d_in[11];
  const float* bs2 = (const float*)d_in[12];
  const float* bu2 = (const float*)d_in[13];
  const float* bng = (const float*)d_in[14];
  const float* bnb = (const float*)d_in[15];
  const int* gg_src  = (const int*)d_in[16];
  const int* gg_dst  = (const int*)d_in[17];
  const int* gda_src = (const int*)d_in[18];
  const int* gda_dst = (const int*)d_in[19];
  const int* lsrc = (const int*)d_in[20];
  const int* ldst = (const int*)d_in[21];

  char* ws = (char*)d_ws;
  size_t off = 0;
  auto alloc = [&](size_t bytes)->void*{
    void* p = ws + off; off += (bytes + 255) & ~(size_t)255; return p;
  };
  int* gcur    = (int*)alloc(960*4);        // zero-init (memset below covers gcur+bnsum)
  float* bnsum = (float*)alloc(2*256*4);
  int2* se_all = (int2*)alloc((size_t)(NG+ND+NG)*8);
  int* col     = (int*)alloc((size_t)TB*CAP*4);
  unsigned* pk = (unsigned*)alloc((size_t)TB*CAP*4);
  float* AB  = (float*)alloc(2*98304*4);
  float* cv  = (float*)alloc(2*384*4);
  float* cg1 = (float*)alloc(128*4);
  float* cd1 = (float*)alloc(128*4);
  float* cg2 = (float*)alloc(128*4);
  float* cd2 = (float*)alloc(128*4);
  bf16* Wg1  = (bf16*)alloc(49152*2);
  bf16* Wp1  = (bf16*)alloc(32768*2);
  bf16* Wg2  = (bf16*)alloc(49152*2);
  bf16* Wp2  = (bf16*)alloc(32768*2);
  bf16* xgb  = (bf16*)alloc((size_t)NG*DH*2);
  bf16* xdb  = (bf16*)alloc((size_t)ND*DH*2);
  unsigned* xg8  = (unsigned*)alloc((size_t)NG*DH);
  unsigned* xd8  = (unsigned*)alloc((size_t)ND*DH);
  unsigned* Xg28 = (unsigned*)alloc((size_t)NG*DH);
  unsigned* Xd28 = (unsigned*)alloc((size_t)ND*DH);
  bf16* aggGGb  = (bf16*)alloc((size_t)NG*DH*2);
  bf16* aggREVb = (bf16*)alloc((size_t)NG*DH*2);
  bf16* aggGDAb = (bf16*)alloc((size_t)ND*DH*2);
  bf16* Xg2b = (bf16*)alloc((size_t)NG*DH*2);
  bf16* Xd2b = (bf16*)alloc((size_t)ND*DH*2);
  bf16* outgb = (bf16*)alloc((size_t)NG*DH*2);
  bf16* outdb = (bf16*)alloc((size_t)ND*DH*2);

  // zero gcur (960 ints) + bnsum (512 floats) in one memset (contiguous region)
  hipMemsetAsync(gcur, 0, 960*4 + 512*4, stream);

  // --- CSR build: capacity-padded, 2 dispatches ---
  {
    dim3 gs(196, 3);
    k_scatter1<<<gs,256,0,stream>>>(gg_dst, gg_src, gda_dst, gda_src, gcur, pk);
    k_csr2<<<TB,256,0,stream>>>(pk, gcur, se_all, col);
  }

  // --- prep: weight compose + bias + f2b/f2fp8 (one dispatch) ---
  k_prep<<<771 + PREP_F2B_BLOCKS,256,0,stream>>>(
      Wd1, Ws1, Wu1, Wd2, Ws2, Wu2, bd1, bs1, bu1, bd2, bs2, bu2,
      AB, cv, x_gene, x_dis, (unsigned short*)xgb, (unsigned short*)xdb, xg8, xd8);
  k_pack<<<640,256,0,stream>>>(AB, cv, Wg1, Wp1, Wg2, Wp2, cg1, cd1, cg2, cd2);

  // --- layer 1 ---
  k_agg<<<(NG+ND+NG)*16/256,256,0,stream>>>(xg8, xd8, se_all, col, aggGGb, aggGDAb, aggREVb);
  k_gemm<<<GBGENE+GBDIS,256,0,stream>>>(xgb, aggGGb, aggREVb, Wg1, cg1, (unsigned short*)outgb,
                                        xdb, aggGDAb, Wp1, cd1, (unsigned short*)outdb);
  k_bn_stats<<<SBG+SBD,256,0,stream>>>(outgb, outdb, bnsum);
  k_bn_apply<<<1024,256,0,stream>>>(outgb, outdb, bnsum, bng, bnb,
                                    (unsigned short*)Xg2b, (unsigned short*)Xd2b,
                                    (uint2*)Xg28, (uint2*)Xd28);

  // --- layer 2 ---
  k_agg<<<(NG+ND+NG)*16/256,256,0,stream>>>(Xg28, Xd28, se_all, col, aggGGb, aggGDAb, aggREVb);
  k_gemm<<<GBGENE+GBDIS,256,0,stream>>>(Xg2b, aggGGb, aggREVb, Wg2, cg2, (unsigned short*)outgb,
                                        Xd2b, aggGDAb, Wp2, cd2, (unsigned short*)outdb);

  // --- decoder ---
  k_decode<<<ELAB*16/2/256,256,0,stream>>>(outgb, outdb, lsrc, ldst, (float*)d_out, ELAB);
}